// Round 1
// baseline (9871.820 us; speedup 1.0000x reference)
//
#include <hip/hip_runtime.h>
#include <hip/hip_bf16.h>
#include <cstdint>
#include <cstddef>

// ---------------- constants ----------------
// N=30000 nodes, E=480000 edges, HID=256, SW=512, NB=128 bundles of dim 2.

constexpr int BM = 128, BN = 128, BK = 8, TM = 8, TN = 8; // fp32 tiled GEMM

__device__ __forceinline__ float gelu_exact(float x) {
  return 0.5f * x * (1.0f + erff(x * 0.7071067811865475f));
}

// ---------------- CSR build ----------------
__global__ void k_hist(const int* __restrict__ dst, int* __restrict__ deg, int E) {
  int i = blockIdx.x * 256 + threadIdx.x;
  if (i < E) atomicAdd(&deg[dst[i]], 1);
}

__global__ __launch_bounds__(1024)
void k_scan(const int* __restrict__ deg, int* __restrict__ rp, int* __restrict__ cur, int Nn) {
  __shared__ int part[1024];
  int t = threadIdx.x;
  int chunk = (Nn + 1023) >> 10;
  int s0 = t * chunk;
  int e0 = s0 + chunk; if (e0 > Nn) e0 = Nn;
  int s = 0;
  for (int i = s0; i < e0; ++i) s += deg[i];
  part[t] = s;
  __syncthreads();
  for (int off = 1; off < 1024; off <<= 1) {
    int v = (t >= off) ? part[t - off] : 0;
    __syncthreads();
    part[t] += v;
    __syncthreads();
  }
  int base = (t == 0) ? 0 : part[t - 1];
  for (int i = s0; i < e0; ++i) {
    rp[i] = base; cur[i] = base; base += deg[i];
  }
  if (t == 0) rp[Nn] = part[1023];
}

__global__ void k_fill(const int* __restrict__ src, const int* __restrict__ dst,
                       int* __restrict__ cur, int* __restrict__ srcs, int E) {
  int i = blockIdx.x * 256 + threadIdx.x;
  if (i < E) {
    int p = atomicAdd(&cur[dst[i]], 1);
    srcs[p] = src[i];
  }
}

// ---------------- GEMM: C = [res +] act(A@W + bias) ----------------
// A columns [0,K1) from A1 (lda=K1), [K1,K1+K2) from A2 (lda=K2). W is [K1+K2, N] row-major.
template<int ACT, bool RES, bool DUAL>
__global__ __launch_bounds__(256)
void k_gemm(const float* __restrict__ A1, const float* __restrict__ A2,
            int K1, int K2,
            const float* __restrict__ W, const float* __restrict__ bias,
            const float* __restrict__ R, float* __restrict__ C,
            int M, int N) {
  __shared__ float As[BK][BM];
  __shared__ float Bs[BK][BN];
  const int tid = threadIdx.x;
  const int m0 = blockIdx.x * BM;
  const int n0 = blockIdx.y * BN;
  const int tx = tid & 15, ty = tid >> 4;
  const int Ktot = K1 + K2;

  const int am = tid >> 1;        // 0..127  (A tile row)
  const int ak = (tid & 1) * 4;   // 0 or 4  (A tile col group)
  const int bk = tid >> 5;        // 0..7    (B tile row)
  const int bn = (tid & 31) * 4;  // B tile col group

  float acc[TM][TN];
#pragma unroll
  for (int i = 0; i < TM; ++i)
#pragma unroll
    for (int j = 0; j < TN; ++j) acc[i][j] = 0.f;

  for (int k0 = 0; k0 < Ktot; k0 += BK) {
    const float* Asrc; int kc, lda;
    if (!DUAL || k0 < K1) { Asrc = A1; kc = k0; lda = K1; }
    else                  { Asrc = A2; kc = k0 - K1; lda = K2; }

    float4 av = make_float4(0.f, 0.f, 0.f, 0.f);
    int gm = m0 + am;
    if (gm < M) av = *reinterpret_cast<const float4*>(Asrc + (size_t)gm * lda + kc + ak);
    float4 bv = *reinterpret_cast<const float4*>(W + (size_t)(k0 + bk) * N + n0 + bn);
    As[ak + 0][am] = av.x; As[ak + 1][am] = av.y;
    As[ak + 2][am] = av.z; As[ak + 3][am] = av.w;
    *reinterpret_cast<float4*>(&Bs[bk][bn]) = bv;
    __syncthreads();

#pragma unroll
    for (int kk = 0; kk < BK; ++kk) {
      float a[TM], b[TN];
      *reinterpret_cast<float4*>(&a[0]) = *reinterpret_cast<const float4*>(&As[kk][ty * TM]);
      *reinterpret_cast<float4*>(&a[4]) = *reinterpret_cast<const float4*>(&As[kk][ty * TM + 4]);
      *reinterpret_cast<float4*>(&b[0]) = *reinterpret_cast<const float4*>(&Bs[kk][tx * TN]);
      *reinterpret_cast<float4*>(&b[4]) = *reinterpret_cast<const float4*>(&Bs[kk][tx * TN + 4]);
#pragma unroll
      for (int i = 0; i < TM; ++i)
#pragma unroll
        for (int j = 0; j < TN; ++j)
          acc[i][j] = fmaf(a[i], b[j], acc[i][j]);
    }
    __syncthreads();
  }

#pragma unroll
  for (int i = 0; i < TM; ++i) {
    int gm = m0 + ty * TM + i;
    if (gm >= M) continue;
#pragma unroll
    for (int j4 = 0; j4 < TN; j4 += 4) {
      int gn = n0 + tx * TN + j4;
      float4 r;
      r.x = acc[i][j4 + 0] + bias[gn + 0];
      r.y = acc[i][j4 + 1] + bias[gn + 1];
      r.z = acc[i][j4 + 2] + bias[gn + 2];
      r.w = acc[i][j4 + 3] + bias[gn + 3];
      if (ACT == 1) {
        r.x = gelu_exact(r.x); r.y = gelu_exact(r.y);
        r.z = gelu_exact(r.z); r.w = gelu_exact(r.w);
      }
      if (RES) {
        float4 rv = *reinterpret_cast<const float4*>(R + (size_t)gm * N + gn);
        r.x += rv.x; r.y += rv.y; r.z += rv.z; r.w += rv.w;
      }
      *reinterpret_cast<float4*>(C + (size_t)gm * N + gn) = r;
    }
  }
}

// ---------------- mean aggregation (one wave per node) ----------------
// out[v] = mean_{u->v} X[u]; if ROT: out = O^T * mean (per 2-dim bundle, o = (c,s) pairs)
template<int W, bool ROT>
__global__ __launch_bounds__(256)
void k_agg(const float* __restrict__ X, const int* __restrict__ rp,
           const int* __restrict__ srcs, const float* __restrict__ o,
           float* __restrict__ out, int Nn) {
  int wid = (blockIdx.x * 256 + threadIdx.x) >> 6;
  int lane = threadIdx.x & 63;
  if (wid >= Nn) return;
  constexpr int P = W / 256;
  float a[P][4];
#pragma unroll
  for (int p = 0; p < P; ++p) { a[p][0] = 0.f; a[p][1] = 0.f; a[p][2] = 0.f; a[p][3] = 0.f; }
  int beg = rp[wid], end = rp[wid + 1];
  for (int e = beg; e < end; ++e) {
    int s = srcs[e];
    const float4* row = reinterpret_cast<const float4*>(X + (size_t)s * W);
#pragma unroll
    for (int p = 0; p < P; ++p) {
      float4 v = row[p * 64 + lane];
      a[p][0] += v.x; a[p][1] += v.y; a[p][2] += v.z; a[p][3] += v.w;
    }
  }
  float inv = (end > beg) ? 1.0f / (float)(end - beg) : 0.0f;
#pragma unroll
  for (int p = 0; p < P; ++p) { a[p][0] *= inv; a[p][1] *= inv; a[p][2] *= inv; a[p][3] *= inv; }
  if (ROT) {
    float4 oc = reinterpret_cast<const float4*>(o + (size_t)wid * 256)[lane]; // c0,s0,c1,s1
    float4 m;
    m.x = oc.x * a[0][0] - oc.y * a[0][1];
    m.y = oc.y * a[0][0] + oc.x * a[0][1];
    m.z = oc.z * a[0][2] - oc.w * a[0][3];
    m.w = oc.w * a[0][2] + oc.z * a[0][3];
    reinterpret_cast<float4*>(out + (size_t)wid * W)[lane] = m;
  } else {
#pragma unroll
    for (int p = 0; p < P; ++p) {
      float4 v = make_float4(a[p][0], a[p][1], a[p][2], a[p][3]);
      reinterpret_cast<float4*>(out + (size_t)wid * W)[p * 64 + lane] = v;
    }
  }
}

// ---------------- Householder(2x2) -> rotation params ----------------
// per bundle: x = nr[n][4b+2]; c = (x^2-1)/(1+x^2), s = 2x/(1+x^2); o[n][2b]=c, o[n][2b+1]=s
__global__ void k_oparams(const float* __restrict__ nr, float* __restrict__ o, int total) {
  int idx = blockIdx.x * 256 + threadIdx.x;
  if (idx >= total) return;
  float x = nr[(size_t)idx * 4 + 2];
  float inv = 1.0f / (1.0f + x * x);
  o[(size_t)idx * 2]     = (x * x - 1.0f) * inv;
  o[(size_t)idx * 2 + 1] = 2.0f * x * inv;
}

// ---------------- LayerNorm + rotate-into-frame (one wave per node) ----------------
__global__ __launch_bounds__(256)
void k_ln_rot(const float* __restrict__ h, const float* __restrict__ o,
              const float* __restrict__ g, const float* __restrict__ b,
              float* __restrict__ hn, float* __restrict__ y, int Nn) {
  int wid = (blockIdx.x * 256 + threadIdx.x) >> 6;
  int lane = threadIdx.x & 63;
  if (wid >= Nn) return;
  float4 v = reinterpret_cast<const float4*>(h + (size_t)wid * 256)[lane];
  float s = v.x + v.y + v.z + v.w;
  float ss = v.x * v.x + v.y * v.y + v.z * v.z + v.w * v.w;
#pragma unroll
  for (int off = 1; off < 64; off <<= 1) { s += __shfl_xor(s, off); ss += __shfl_xor(ss, off); }
  float mean = s * (1.0f / 256.0f);
  float var = ss * (1.0f / 256.0f) - mean * mean;
  float rs = rsqrtf(var + 1e-5f);
  float4 gg = reinterpret_cast<const float4*>(g)[lane];
  float4 bb = reinterpret_cast<const float4*>(b)[lane];
  float4 hv;
  hv.x = (v.x - mean) * rs * gg.x + bb.x;
  hv.y = (v.y - mean) * rs * gg.y + bb.y;
  hv.z = (v.z - mean) * rs * gg.z + bb.z;
  hv.w = (v.w - mean) * rs * gg.w + bb.w;
  reinterpret_cast<float4*>(hn + (size_t)wid * 256)[lane] = hv;
  float4 oc = reinterpret_cast<const float4*>(o + (size_t)wid * 256)[lane]; // c0,s0,c1,s1
  float4 yv;
  yv.x =  oc.x * hv.x + oc.y * hv.y;
  yv.y = -oc.y * hv.x + oc.x * hv.y;
  yv.z =  oc.z * hv.z + oc.w * hv.w;
  yv.w = -oc.w * hv.z + oc.z * hv.w;
  reinterpret_cast<float4*>(y + (size_t)wid * 256)[lane] = yv;
}

// ---------------- final: out = LN(h) @ w_out + b_out (one wave per node) ----------------
__global__ __launch_bounds__(256)
void k_final(const float* __restrict__ h, const float* __restrict__ g,
             const float* __restrict__ b, const float* __restrict__ wout,
             const float* __restrict__ bout, float* __restrict__ out, int Nn) {
  int wid = (blockIdx.x * 256 + threadIdx.x) >> 6;
  int lane = threadIdx.x & 63;
  if (wid >= Nn) return;
  float4 v = reinterpret_cast<const float4*>(h + (size_t)wid * 256)[lane];
  float s = v.x + v.y + v.z + v.w;
  float ss = v.x * v.x + v.y * v.y + v.z * v.z + v.w * v.w;
#pragma unroll
  for (int off = 1; off < 64; off <<= 1) { s += __shfl_xor(s, off); ss += __shfl_xor(ss, off); }
  float mean = s * (1.0f / 256.0f);
  float var = ss * (1.0f / 256.0f) - mean * mean;
  float rs = rsqrtf(var + 1e-5f);
  float4 gg = reinterpret_cast<const float4*>(g)[lane];
  float4 bb = reinterpret_cast<const float4*>(b)[lane];
  float hv[4];
  hv[0] = (v.x - mean) * rs * gg.x + bb.x;
  hv[1] = (v.y - mean) * rs * gg.y + bb.y;
  hv[2] = (v.z - mean) * rs * gg.z + bb.z;
  hv[3] = (v.w - mean) * rs * gg.w + bb.w;
  int c0 = lane * 4;
  float dots[5];
#pragma unroll
  for (int j = 0; j < 5; ++j) {
    float p = hv[0] * wout[(size_t)(c0 + 0) * 5 + j] + hv[1] * wout[(size_t)(c0 + 1) * 5 + j]
            + hv[2] * wout[(size_t)(c0 + 2) * 5 + j] + hv[3] * wout[(size_t)(c0 + 3) * 5 + j];
#pragma unroll
    for (int off = 1; off < 64; off <<= 1) p += __shfl_xor(p, off);
    dots[j] = p;
  }
  if (lane == 0) {
#pragma unroll
    for (int j = 0; j < 5; ++j) out[(size_t)wid * 5 + j] = dots[j] + bout[j];
  }
}

// ---------------- host-side launch ----------------
extern "C" void kernel_launch(void* const* d_in, const int* in_sizes, int n_in,
                              void* d_out, int out_size, void* d_ws, size_t ws_size,
                              hipStream_t stream) {
  const float* x       = (const float*)d_in[0];
  const int*   ei      = (const int*)  d_in[1];
  const float* w_in    = (const float*)d_in[2];
  const float* b_in    = (const float*)d_in[3];
  const float* se_in_w = (const float*)d_in[4];
  const float* se_in_b = (const float*)d_in[5];
  const float* sage_w1 = (const float*)d_in[6];
  const float* sage_b1 = (const float*)d_in[7];
  const float* sage_w2 = (const float*)d_in[8];
  const float* sage_b2 = (const float*)d_in[9];
  const float* se_out_w= (const float*)d_in[10];
  const float* se_out_b= (const float*)d_in[11];
  const float* enc_w1  = (const float*)d_in[12];
  const float* enc_b1  = (const float*)d_in[13];
  const float* enc_w2  = (const float*)d_in[14];
  const float* enc_b2  = (const float*)d_in[15];
  const float* ln_g    = (const float*)d_in[16];
  const float* ln_b    = (const float*)d_in[17];
  const float* bdl_w1  = (const float*)d_in[18];
  const float* bdl_b1  = (const float*)d_in[19];
  const float* bdl_w2  = (const float*)d_in[20];
  const float* bdl_b2  = (const float*)d_in[21];
  const float* oln_g   = (const float*)d_in[22];
  const float* oln_b   = (const float*)d_in[23];
  const float* w_out   = (const float*)d_in[24];
  const float* b_out   = (const float*)d_in[25];
  float* out = (float*)d_out;

  const int HID = 256, SW = 512;
  const int N = in_sizes[0] / HID;   // 30000
  const int E = in_sizes[1] / 2;     // 480000

  // workspace layout (floats then ints), ~248 MB
  float* ws = (float*)d_ws;
  float* h  = ws;                          // [N,256]
  float* z  = h + (size_t)N * HID;         // [N,512]
  float* t  = z + (size_t)N * SW;          // [N,512]
  float* u  = t + (size_t)N * SW;          // [N,512]
  float* o  = u + (size_t)N * SW;          // [N,256] rotation params (c,s)*128
  int* deg  = (int*)(o + (size_t)N * HID); // [N]
  int* rp   = deg + N;                     // [N+1]
  int* cur  = rp + N + 1;                  // [N]
  int* srcs = cur + N;                     // [E]
  size_t need = ((size_t)N * (HID * 2 + SW * 3)) * 4 + ((size_t)3 * N + 1 + E) * 4;
  if (ws_size < need) return;  // workspace too small; fail loudly via wrong output

  float* hn  = z;                      // [N,256] after nr consumed
  float* y   = z + (size_t)N * HID;    // [N,256]
  float* msg = t;                      // [N,256]
  float* g2  = u;                      // [N,256]

  const int* esrc = ei;
  const int* edst = ei + E;

  auto cdiv = [](int a, int b) { return (a + b - 1) / b; };
  dim3 blk(256);
  dim3 g_gh(cdiv(N, BM), HID / BN);   // GEMM grid, N-dim 256
  dim3 g_gs(cdiv(N, BM), SW / BN);    // GEMM grid, N-dim 512
  int gw = cdiv(N * 64, 256);         // one wave per node

  // ---- CSR build ----
  hipMemsetAsync(deg, 0, sizeof(int) * N, stream);
  k_hist<<<cdiv(E, 256), blk, 0, stream>>>(edst, deg, E);
  k_scan<<<1, 1024, 0, stream>>>(deg, rp, cur, N);
  k_fill<<<cdiv(E, 256), blk, 0, stream>>>(esrc, edst, cur, srcs, E);

  // ---- h = gelu(x @ w_in + b_in) ----
  k_gemm<1, false, false><<<g_gh, blk, 0, stream>>>(x, nullptr, HID, 0, w_in, b_in, nullptr, h, N, HID);

  for (int k = 0; k < 2; ++k) {
    // struct encoder (weights shared across k)
    k_gemm<1, false, false><<<g_gs, blk, 0, stream>>>(h, nullptr, HID, 0, se_in_w, se_in_b, nullptr, z, N, SW);
    for (int i = 0; i < 5; ++i) {
      k_agg<512, false><<<gw, blk, 0, stream>>>(z, rp, srcs, nullptr, t, N);
      k_gemm<1, false, true><<<g_gs, blk, 0, stream>>>(z, t, SW, SW,
          sage_w1 + (size_t)i * 2 * SW * SW, sage_b1 + (size_t)i * SW, nullptr, u, N, SW);
      k_gemm<0, true, false><<<g_gs, blk, 0, stream>>>(u, nullptr, SW, 0,
          sage_w2 + (size_t)i * SW * SW, sage_b2 + (size_t)i * SW, z, z, N, SW);
    }
    k_gemm<0, false, false><<<g_gs, blk, 0, stream>>>(z, nullptr, SW, 0, se_out_w, se_out_b, nullptr, t, N, SW);
    // nr = gelu(enc @ enc_w1 + b) @ enc_w2 + b
    k_gemm<1, false, false><<<g_gs, blk, 0, stream>>>(t, nullptr, SW, 0,
        enc_w1 + (size_t)k * SW * SW, enc_b1 + (size_t)k * SW, nullptr, u, N, SW);
    k_gemm<0, false, false><<<g_gs, blk, 0, stream>>>(u, nullptr, SW, 0,
        enc_w2 + (size_t)k * SW * SW, enc_b2 + (size_t)k * SW, nullptr, z, N, SW);
    // rotation params from nr (in z)
    k_oparams<<<cdiv(N * 128, 256), blk, 0, stream>>>(z, o, N * 128);
    // hn = LN(h), y = O @ hn  (overwrites z region)
    k_ln_rot<<<gw, blk, 0, stream>>>(h, o, ln_g + (size_t)k * HID, ln_b + (size_t)k * HID, hn, y, N);
    // msg = O^T @ mean_agg(y)
    k_agg<256, true><<<gw, blk, 0, stream>>>(y, rp, srcs, o, msg, N);
    // h = h + gelu([hn|msg] @ bdl_w1 + b1) @ bdl_w2 + b2
    k_gemm<1, false, true><<<g_gh, blk, 0, stream>>>(hn, msg, HID, HID,
        bdl_w1 + (size_t)k * 2 * HID * HID, bdl_b1 + (size_t)k * HID, nullptr, g2, N, HID);
    k_gemm<0, true, false><<<g_gh, blk, 0, stream>>>(g2, nullptr, HID, 0,
        bdl_w2 + (size_t)k * HID * HID, bdl_b2 + (size_t)k * HID, h, h, N, HID);
  }

  k_final<<<gw, blk, 0, stream>>>(h, oln_g, oln_b, w_out, b_out, out, N);
}

// Round 2
// 2974.114 us; speedup vs baseline: 3.3192x; 3.3192x over previous
//
#include <hip/hip_runtime.h>
#include <hip/hip_bf16.h>
#include <cstdint>
#include <cstddef>

// N=30000 nodes, E=480000 edges, HID=256, SW=512, NB=128 bundles of dim 2.
// Householder(2x2) collapses to planar rotation: x=X[1,0]; c=(x^2-1)/(1+x^2), s=2x/(1+x^2).

typedef __attribute__((ext_vector_type(8))) short short8;
typedef __attribute__((ext_vector_type(4))) float f32x4;

__device__ __forceinline__ float gelu_exact(float x) {
  return 0.5f * x * (1.0f + erff(x * 0.7071067811865475f));
}
__device__ __forceinline__ unsigned short f2bf(float f) {
  __hip_bfloat16 b = __float2bfloat16(f);
  return *reinterpret_cast<unsigned short*>(&b);
}
__device__ __forceinline__ float bf2f(unsigned short u) {
  return __uint_as_float((unsigned)u << 16);
}
__device__ __forceinline__ float bflo(unsigned u) { return __uint_as_float(u << 16); }
__device__ __forceinline__ float bfhi(unsigned u) { return __uint_as_float(u & 0xffff0000u); }
__device__ __forceinline__ unsigned packbf(float f0, float f1) {
  return (unsigned)f2bf(f0) | ((unsigned)f2bf(f1) << 16);
}
__device__ __forceinline__ void gload16(const void* g, void* l) {
  __builtin_amdgcn_global_load_lds((const __attribute__((address_space(1))) void*)g,
                                   (__attribute__((address_space(3))) void*)l, 16, 0, 0);
}

// ---------------- CSR build ----------------
__global__ void k_hist(const int* __restrict__ dst, int* __restrict__ deg, int E) {
  int i = blockIdx.x * 256 + threadIdx.x;
  if (i < E) atomicAdd(&deg[dst[i]], 1);
}

__global__ __launch_bounds__(1024)
void k_scan(const int* __restrict__ deg, int* __restrict__ rp, int* __restrict__ cur, int Nn) {
  __shared__ int part[1024];
  int t = threadIdx.x;
  int chunk = (Nn + 1023) >> 10;
  int s0 = t * chunk;
  int e0 = s0 + chunk; if (e0 > Nn) e0 = Nn;
  int s = 0;
  for (int i = s0; i < e0; ++i) s += deg[i];
  part[t] = s;
  __syncthreads();
  for (int off = 1; off < 1024; off <<= 1) {
    int v = (t >= off) ? part[t - off] : 0;
    __syncthreads();
    part[t] += v;
    __syncthreads();
  }
  int base = (t == 0) ? 0 : part[t - 1];
  for (int i = s0; i < e0; ++i) {
    rp[i] = base; cur[i] = base; base += deg[i];
  }
  if (t == 0) rp[Nn] = part[1023];
}

__global__ void k_fill(const int* __restrict__ src, const int* __restrict__ dst,
                       int* __restrict__ cur, int* __restrict__ srcs, int E) {
  int i = blockIdx.x * 256 + threadIdx.x;
  if (i < E) {
    int p = atomicAdd(&cur[dst[i]], 1);
    srcs[p] = src[i];
  }
}

// ---------------- weight transpose fp32 [K,N] -> bf16 [N,K] ----------------
__global__ void k_wT(const float* __restrict__ W, unsigned short* __restrict__ Wt, int K, int Nc) {
  int idx = blockIdx.x * 256 + threadIdx.x;
  if (idx >= K * Nc) return;
  int k = idx % K, n = idx / K;                       // k fastest -> coalesced writes
  Wt[(size_t)n * K + k] = f2bf(W[(size_t)k * Nc + n]);
}

__global__ void k_cast(const float* __restrict__ src, unsigned short* __restrict__ dst, int n) {
  int i = blockIdx.x * 256 + threadIdx.x;
  if (i < n) dst[i] = f2bf(src[i]);
}

// ---------------- bf16 MFMA GEMM ----------------
// C = [R +] act(A @ W + bias), A bf16 row-major (dual-source concat along K),
// Wt = W^T bf16 [Nc, Ktot] row-major. Accumulate fp32. Tile 128x128, BK=64, 4 waves.
template<int ACT, bool RES, bool DUAL, bool W32, bool WBF>
__global__ __launch_bounds__(256)
void k_mfma(const unsigned short* __restrict__ A1, const unsigned short* __restrict__ A2,
            int K1, int K2,
            const unsigned short* __restrict__ Wt, const float* __restrict__ bias,
            const float* R, float* C32, unsigned short* Cbf, int M, int Nc) {
  __shared__ unsigned short As[128 * 64];   // [row][64] bf16, 128B rows, XOR-swizzled segs
  __shared__ unsigned short Bs[128 * 64];
  const int tid = threadIdx.x;
  const int lane = tid & 63, wv = tid >> 6;
  const int m0 = blockIdx.x * 128, n0 = blockIdx.y * 128;
  const int wr = (wv >> 1) * 64, wc = (wv & 1) * 64;  // wave's 64x64 subtile
  const int rA = lane & 15, kg = lane >> 4;
  const int Ktot = K1 + K2;

  f32x4 acc[4][4];
#pragma unroll
  for (int m = 0; m < 4; ++m)
#pragma unroll
    for (int n = 0; n < 4; ++n)
#pragma unroll
      for (int r = 0; r < 4; ++r) acc[m][n][r] = 0.f;

  for (int k0 = 0; k0 < Ktot; k0 += 64) {
    const unsigned short* Asrc; int kc, lda;
    if (!DUAL || k0 < K1) { Asrc = A1; kc = k0; lda = K1; }
    else                  { Asrc = A2; kc = k0 - K1; lda = K2; }
    __syncthreads();   // all waves done reading previous tile
    // stage A,B: 1024 16B-chunks each, 4 issues of 256 threads.
    // linear LDS dest; swizzle applied on the GLOBAL source k-segment (involution).
#pragma unroll
    for (int is = 0; is < 4; ++is) {
      int chunk = is * 256 + tid;
      int row = chunk >> 3, seg = chunk & 7;
      int ks = seg ^ (row & 7);
      int gm = m0 + row; gm = gm < M ? gm : M - 1;
      gload16(Asrc + (size_t)gm * lda + kc + ks * 8,
              (char*)As + (size_t)(is * 256 + (wv << 6)) * 16);
      gload16(Wt + (size_t)(n0 + row) * Ktot + k0 + ks * 8,
              (char*)Bs + (size_t)(is * 256 + (wv << 6)) * 16);
    }
    __syncthreads();   // staged data visible (syncthreads drains vmcnt)
#pragma unroll
    for (int kk = 0; kk < 2; ++kk) {
      short8 af[4], bfr[4];
#pragma unroll
      for (int m = 0; m < 4; ++m) {
        int row = wr + m * 16 + rA;
        int ks = (kk * 4 + kg) ^ (row & 7);
        af[m] = *reinterpret_cast<const short8*>((const char*)As + row * 128 + ks * 16);
      }
#pragma unroll
      for (int n = 0; n < 4; ++n) {
        int col = wc + n * 16 + rA;
        int ks = (kk * 4 + kg) ^ (col & 7);
        bfr[n] = *reinterpret_cast<const short8*>((const char*)Bs + col * 128 + ks * 16);
      }
#pragma unroll
      for (int m = 0; m < 4; ++m)
#pragma unroll
        for (int n = 0; n < 4; ++n)
          acc[m][n] = __builtin_amdgcn_mfma_f32_16x16x32_bf16(af[m], bfr[n], acc[m][n], 0, 0, 0);
    }
  }

  // epilogue: C/D layout col=lane&15, row=(lane>>4)*4+reg  [m89]
#pragma unroll
  for (int m = 0; m < 4; ++m) {
    int gr0 = m0 + wr + m * 16 + kg * 4;
#pragma unroll
    for (int n = 0; n < 4; ++n) {
      int gc = n0 + wc + n * 16 + rA;
      float bv = bias[gc];
#pragma unroll
      for (int r = 0; r < 4; ++r) {
        int gr = gr0 + r;
        if (gr < M) {
          float v = acc[m][n][r] + bv;
          if (ACT == 1) v = gelu_exact(v);
          if (RES) v += R[(size_t)gr * Nc + gc];
          if (W32) C32[(size_t)gr * Nc + gc] = v;
          if (WBF) Cbf[(size_t)gr * Nc + gc] = f2bf(v);
        }
      }
    }
  }
}

// ---------------- mean aggregation over bf16 rows (one wave per node) ----------------
template<int W, bool ROT>
__global__ __launch_bounds__(256)
void k_agg(const unsigned short* __restrict__ X, const int* __restrict__ rp,
           const int* __restrict__ srcs, const float* __restrict__ o,
           unsigned short* __restrict__ out, int Nn) {
  int wid = (blockIdx.x * 256 + threadIdx.x) >> 6;
  int lane = threadIdx.x & 63;
  if (wid >= Nn) return;
  constexpr int PE = W / 64;    // bf16 elems per lane: 8 (W=512) or 4 (W=256)
  float a[PE];
#pragma unroll
  for (int p = 0; p < PE; ++p) a[p] = 0.f;
  int beg = rp[wid], end = rp[wid + 1];
  for (int e = beg; e < end; ++e) {
    int s = srcs[e];
    const unsigned* row = reinterpret_cast<const unsigned*>(X + (size_t)s * W) + lane * (PE / 2);
    if (PE == 8) {
      uint4 v = *reinterpret_cast<const uint4*>(row);
      a[0] += bflo(v.x); a[1] += bfhi(v.x); a[2] += bflo(v.y); a[3] += bfhi(v.y);
      a[4] += bflo(v.z); a[5] += bfhi(v.z); a[6] += bflo(v.w); a[7] += bfhi(v.w);
    } else {
      uint2 v = *reinterpret_cast<const uint2*>(row);
      a[0] += bflo(v.x); a[1] += bfhi(v.x); a[2] += bflo(v.y); a[3] += bfhi(v.y);
    }
  }
  float inv = (end > beg) ? 1.0f / (float)(end - beg) : 0.0f;
#pragma unroll
  for (int p = 0; p < PE; ++p) a[p] *= inv;
  if (ROT) {
    float4 oc = *reinterpret_cast<const float4*>(o + (size_t)wid * 256 + lane * 4); // c0,s0,c1,s1
    float m0 = oc.x * a[0] - oc.y * a[1];
    float m1 = oc.y * a[0] + oc.x * a[1];
    float m2 = oc.z * a[2] - oc.w * a[3];
    float m3 = oc.w * a[2] + oc.z * a[3];
    a[0] = m0; a[1] = m1; a[2] = m2; a[3] = m3;
  }
  unsigned short* op = out + (size_t)wid * W + lane * PE;
  if (PE == 8) {
    uint4 rv;
    rv.x = packbf(a[0], a[1]); rv.y = packbf(a[2], a[3]);
    rv.z = packbf(a[4], a[5]); rv.w = packbf(a[6], a[7]);
    *reinterpret_cast<uint4*>(op) = rv;
  } else {
    uint2 rv;
    rv.x = packbf(a[0], a[1]); rv.y = packbf(a[2], a[3]);
    *reinterpret_cast<uint2*>(op) = rv;
  }
}

// ---------------- Householder(2x2) -> rotation params (nr is bf16) ----------------
__global__ void k_oparams(const unsigned short* __restrict__ nr, float* __restrict__ o, int total) {
  int idx = blockIdx.x * 256 + threadIdx.x;
  if (idx >= total) return;
  float x = bf2f(nr[(size_t)idx * 4 + 2]);
  float inv = 1.0f / (1.0f + x * x);
  o[(size_t)idx * 2]     = (x * x - 1.0f) * inv;
  o[(size_t)idx * 2 + 1] = 2.0f * x * inv;
}

// ---------------- LayerNorm + rotate-into-frame; bf16 outputs ----------------
__global__ __launch_bounds__(256)
void k_ln_rot(const float* __restrict__ h, const float* __restrict__ o,
              const float* __restrict__ g, const float* __restrict__ b,
              unsigned short* __restrict__ hn, unsigned short* __restrict__ y, int Nn) {
  int wid = (blockIdx.x * 256 + threadIdx.x) >> 6;
  int lane = threadIdx.x & 63;
  if (wid >= Nn) return;
  float4 v = reinterpret_cast<const float4*>(h + (size_t)wid * 256)[lane];
  float s = v.x + v.y + v.z + v.w;
  float ss = v.x * v.x + v.y * v.y + v.z * v.z + v.w * v.w;
#pragma unroll
  for (int off = 1; off < 64; off <<= 1) { s += __shfl_xor(s, off); ss += __shfl_xor(ss, off); }
  float mean = s * (1.0f / 256.0f);
  float var = ss * (1.0f / 256.0f) - mean * mean;
  float rs = rsqrtf(var + 1e-5f);
  float4 gg = reinterpret_cast<const float4*>(g)[lane];
  float4 bb = reinterpret_cast<const float4*>(b)[lane];
  float h0 = (v.x - mean) * rs * gg.x + bb.x;
  float h1 = (v.y - mean) * rs * gg.y + bb.y;
  float h2 = (v.z - mean) * rs * gg.z + bb.z;
  float h3 = (v.w - mean) * rs * gg.w + bb.w;
  uint2 hv; hv.x = packbf(h0, h1); hv.y = packbf(h2, h3);
  *reinterpret_cast<uint2*>(hn + (size_t)wid * 256 + lane * 4) = hv;
  float4 oc = *reinterpret_cast<const float4*>(o + (size_t)wid * 256 + lane * 4); // c0,s0,c1,s1
  float y0 =  oc.x * h0 + oc.y * h1;
  float y1 = -oc.y * h0 + oc.x * h1;
  float y2 =  oc.z * h2 + oc.w * h3;
  float y3 = -oc.w * h2 + oc.z * h3;
  uint2 yv; yv.x = packbf(y0, y1); yv.y = packbf(y2, y3);
  *reinterpret_cast<uint2*>(y + (size_t)wid * 256 + lane * 4) = yv;
}

// ---------------- final: out = LN(h) @ w_out + b_out ----------------
__global__ __launch_bounds__(256)
void k_final(const float* __restrict__ h, const float* __restrict__ g,
             const float* __restrict__ b, const float* __restrict__ wout,
             const float* __restrict__ bout, float* __restrict__ out, int Nn) {
  int wid = (blockIdx.x * 256 + threadIdx.x) >> 6;
  int lane = threadIdx.x & 63;
  if (wid >= Nn) return;
  float4 v = reinterpret_cast<const float4*>(h + (size_t)wid * 256)[lane];
  float s = v.x + v.y + v.z + v.w;
  float ss = v.x * v.x + v.y * v.y + v.z * v.z + v.w * v.w;
#pragma unroll
  for (int off = 1; off < 64; off <<= 1) { s += __shfl_xor(s, off); ss += __shfl_xor(ss, off); }
  float mean = s * (1.0f / 256.0f);
  float var = ss * (1.0f / 256.0f) - mean * mean;
  float rs = rsqrtf(var + 1e-5f);
  float4 gg = reinterpret_cast<const float4*>(g)[lane];
  float4 bb = reinterpret_cast<const float4*>(b)[lane];
  float hv[4];
  hv[0] = (v.x - mean) * rs * gg.x + bb.x;
  hv[1] = (v.y - mean) * rs * gg.y + bb.y;
  hv[2] = (v.z - mean) * rs * gg.z + bb.z;
  hv[3] = (v.w - mean) * rs * gg.w + bb.w;
  int c0 = lane * 4;
  float dots[5];
#pragma unroll
  for (int j = 0; j < 5; ++j) {
    float p = hv[0] * wout[(size_t)(c0 + 0) * 5 + j] + hv[1] * wout[(size_t)(c0 + 1) * 5 + j]
            + hv[2] * wout[(size_t)(c0 + 2) * 5 + j] + hv[3] * wout[(size_t)(c0 + 3) * 5 + j];
#pragma unroll
    for (int off = 1; off < 64; off <<= 1) p += __shfl_xor(p, off);
    dots[j] = p;
  }
  if (lane == 0) {
#pragma unroll
    for (int j = 0; j < 5; ++j) out[(size_t)wid * 5 + j] = dots[j] + bout[j];
  }
}

// ---------------- host-side launch ----------------
extern "C" void kernel_launch(void* const* d_in, const int* in_sizes, int n_in,
                              void* d_out, int out_size, void* d_ws, size_t ws_size,
                              hipStream_t stream) {
  const float* x       = (const float*)d_in[0];
  const int*   ei      = (const int*)  d_in[1];
  const float* w_in    = (const float*)d_in[2];
  const float* b_in    = (const float*)d_in[3];
  const float* se_in_w = (const float*)d_in[4];
  const float* se_in_b = (const float*)d_in[5];
  const float* sage_w1 = (const float*)d_in[6];
  const float* sage_b1 = (const float*)d_in[7];
  const float* sage_w2 = (const float*)d_in[8];
  const float* sage_b2 = (const float*)d_in[9];
  const float* se_out_w= (const float*)d_in[10];
  const float* se_out_b= (const float*)d_in[11];
  const float* enc_w1  = (const float*)d_in[12];
  const float* enc_b1  = (const float*)d_in[13];
  const float* enc_w2  = (const float*)d_in[14];
  const float* enc_b2  = (const float*)d_in[15];
  const float* ln_g    = (const float*)d_in[16];
  const float* ln_b    = (const float*)d_in[17];
  const float* bdl_w1  = (const float*)d_in[18];
  const float* bdl_b1  = (const float*)d_in[19];
  const float* bdl_w2  = (const float*)d_in[20];
  const float* bdl_b2  = (const float*)d_in[21];
  const float* oln_g   = (const float*)d_in[22];
  const float* oln_b   = (const float*)d_in[23];
  const float* w_out   = (const float*)d_in[24];
  const float* b_out   = (const float*)d_in[25];
  float* out = (float*)d_out;

  const int HID = 256, SW = 512;
  const int N = in_sizes[0] / HID;   // 30000
  const int E = in_sizes[1] / 2;     // 480000

  // ---- workspace layout (~244 MB) ----
  float* ws = (float*)d_ws;
  float* h32 = ws;                              // [N,256] fp32 residual carrier
  float* z32 = h32 + (size_t)N * HID;           // [N,512] fp32 residual carrier
  float* o   = z32 + (size_t)N * SW;            // [N,256] rotation (c,s)*128
  unsigned short* h_bf = (unsigned short*)(o + (size_t)N * HID);  // [N,256]
  unsigned short* z_bf = h_bf + (size_t)N * HID;                  // [N,512]
  unsigned short* t_bf = z_bf + (size_t)N * SW;                   // [N,512]
  unsigned short* u_bf = t_bf + (size_t)N * SW;                   // [N,512]
  // weight transposes (bf16 [N,K])
  unsigned short* wts = u_bf + (size_t)N * SW;
  size_t off = 0;
  unsigned short* wt_in    = wts + off; off += 256 * 256;
  unsigned short* wt_se_in = wts + off; off += 512 * 256;
  unsigned short* wt_sage1 = wts + off; off += (size_t)5 * 512 * 1024;
  unsigned short* wt_sage2 = wts + off; off += (size_t)5 * 512 * 512;
  unsigned short* wt_se_out= wts + off; off += 512 * 512;
  unsigned short* wt_enc1  = wts + off; off += (size_t)2 * 512 * 512;
  unsigned short* wt_enc2  = wts + off; off += (size_t)2 * 512 * 512;
  unsigned short* wt_bdl1  = wts + off; off += (size_t)2 * 256 * 512;
  unsigned short* wt_bdl2  = wts + off; off += (size_t)2 * 256 * 256;
  int* deg  = (int*)(wts + off);
  int* rp   = deg + N;
  int* cur  = rp + N + 1;
  int* srcs = cur + N;
  size_t need = (size_t)((char*)(srcs + E) - (char*)d_ws);
  if (ws_size < need) return;

  // aliases (lifetime-disjoint)
  unsigned short* xbf = u_bf;                   // x cast, consumed by first GEMM
  unsigned short* hn  = z_bf;                   // after encoder done, z free
  unsigned short* y   = z_bf + (size_t)N * HID;
  unsigned short* msg = t_bf;                   // nr consumed by k_oparams first
  unsigned short* g2  = u_bf;

  const int* esrc = ei;
  const int* edst = ei + E;

  auto cdiv = [](int a, int b) { return (a + b - 1) / b; };
  dim3 blk(256);
  int gm_blocks = cdiv(N, 128);
  dim3 g_g256(gm_blocks, 2);   // Nc=256
  dim3 g_g512(gm_blocks, 4);   // Nc=512
  int gw = cdiv(N * 64, 256);

  // ---- CSR build ----
  hipMemsetAsync(deg, 0, sizeof(int) * N, stream);
  k_hist<<<cdiv(E, 256), blk, 0, stream>>>(edst, deg, E);
  k_scan<<<1, 1024, 0, stream>>>(deg, rp, cur, N);
  k_fill<<<cdiv(E, 256), blk, 0, stream>>>(esrc, edst, cur, srcs, E);

  // ---- weight transposes to bf16 ----
  auto wT = [&](const float* W, unsigned short* Wt, int K, int Nc) {
    k_wT<<<cdiv(K * Nc, 256), blk, 0, stream>>>(W, Wt, K, Nc);
  };
  wT(w_in, wt_in, 256, 256);
  wT(se_in_w, wt_se_in, 256, 512);
  for (int i = 0; i < 5; ++i) {
    wT(sage_w1 + (size_t)i * 1024 * 512, wt_sage1 + (size_t)i * 512 * 1024, 1024, 512);
    wT(sage_w2 + (size_t)i * 512 * 512,  wt_sage2 + (size_t)i * 512 * 512,  512, 512);
  }
  wT(se_out_w, wt_se_out, 512, 512);
  for (int k = 0; k < 2; ++k) {
    wT(enc_w1 + (size_t)k * 512 * 512, wt_enc1 + (size_t)k * 512 * 512, 512, 512);
    wT(enc_w2 + (size_t)k * 512 * 512, wt_enc2 + (size_t)k * 512 * 512, 512, 512);
    wT(bdl_w1 + (size_t)k * 512 * 256, wt_bdl1 + (size_t)k * 256 * 512, 512, 256);
    wT(bdl_w2 + (size_t)k * 256 * 256, wt_bdl2 + (size_t)k * 256 * 256, 256, 256);
  }
  k_cast<<<cdiv(N * HID, 256), blk, 0, stream>>>(x, xbf, N * HID);

  // ---- h = gelu(x @ w_in + b_in) : fp32 + bf16 ----
  k_mfma<1, false, false, true, true><<<g_g256, blk, 0, stream>>>(
      xbf, nullptr, 256, 0, wt_in, b_in, nullptr, h32, h_bf, N, 256);

  for (int k = 0; k < 2; ++k) {
    // z = gelu(h @ se_in_w + b) : fp32 + bf16
    k_mfma<1, false, false, true, true><<<g_g512, blk, 0, stream>>>(
        h_bf, nullptr, 256, 0, wt_se_in, se_in_b, nullptr, z32, z_bf, N, 512);
    for (int i = 0; i < 5; ++i) {
      k_agg<512, false><<<gw, blk, 0, stream>>>(z_bf, rp, srcs, nullptr, t_bf, N);
      k_mfma<1, false, true, false, true><<<g_g512, blk, 0, stream>>>(
          z_bf, t_bf, 512, 512, wt_sage1 + (size_t)i * 512 * 1024,
          sage_b1 + (size_t)i * SW, nullptr, nullptr, u_bf, N, 512);
      k_mfma<0, true, false, true, true><<<g_g512, blk, 0, stream>>>(
          u_bf, nullptr, 512, 0, wt_sage2 + (size_t)i * 512 * 512,
          sage_b2 + (size_t)i * SW, z32, z32, z_bf, N, 512);
    }
    // enc = z @ se_out_w + b   (bf16 only)
    k_mfma<0, false, false, false, true><<<g_g512, blk, 0, stream>>>(
        z_bf, nullptr, 512, 0, wt_se_out, se_out_b, nullptr, nullptr, t_bf, N, 512);
    // nr = gelu(enc @ enc_w1 + b) @ enc_w2 + b
    k_mfma<1, false, false, false, true><<<g_g512, blk, 0, stream>>>(
        t_bf, nullptr, 512, 0, wt_enc1 + (size_t)k * 512 * 512,
        enc_b1 + (size_t)k * SW, nullptr, nullptr, u_bf, N, 512);
    k_mfma<0, false, false, false, true><<<g_g512, blk, 0, stream>>>(
        u_bf, nullptr, 512, 0, wt_enc2 + (size_t)k * 512 * 512,
        enc_b2 + (size_t)k * SW, nullptr, nullptr, t_bf, N, 512);
    // rotation params; hn=LN(h), y=O@hn; msg=O^T@mean(y)
    k_oparams<<<cdiv(N * 128, 256), blk, 0, stream>>>(t_bf, o, N * 128);
    k_ln_rot<<<gw, blk, 0, stream>>>(h32, o, ln_g + (size_t)k * HID, ln_b + (size_t)k * HID, hn, y, N);
    k_agg<256, true><<<gw, blk, 0, stream>>>(y, rp, srcs, o, msg, N);
    // h = h + gelu([hn|msg] @ bdl_w1 + b1) @ bdl_w2 + b2
    k_mfma<1, false, true, false, true><<<g_g256, blk, 0, stream>>>(
        hn, msg, 256, 256, wt_bdl1 + (size_t)k * 256 * 512,
        bdl_b1 + (size_t)k * HID, nullptr, nullptr, g2, N, 256);
    k_mfma<0, true, false, true, true><<<g_g256, blk, 0, stream>>>(
        g2, nullptr, 256, 0, wt_bdl2 + (size_t)k * 256 * 256,
        bdl_b2 + (size_t)k * HID, h32, h32, h_bf, N, 256);
  }

  k_final<<<gw, blk, 0, stream>>>(h32, oln_g, oln_b, w_out, b_out, out, N);
}

// Round 3
// 2849.062 us; speedup vs baseline: 3.4649x; 1.0439x over previous
//
#include <hip/hip_runtime.h>
#include <hip/hip_bf16.h>
#include <cstdint>
#include <cstddef>

// N=30000 nodes, E=480000 edges, HID=256, SW=512, NB=128 bundles of dim 2.
// Householder(2x2) collapses to planar rotation: x=X[1,0]; c=(x^2-1)/(1+x^2), s=2x/(1+x^2).

typedef __attribute__((ext_vector_type(8))) short short8;
typedef __attribute__((ext_vector_type(4))) float f32x4;

__device__ __forceinline__ float gelu_exact(float x) {
  return 0.5f * x * (1.0f + erff(x * 0.7071067811865475f));
}
__device__ __forceinline__ unsigned short f2bf(float f) {
  __hip_bfloat16 b = __float2bfloat16(f);
  return *reinterpret_cast<unsigned short*>(&b);
}
__device__ __forceinline__ float bf2f(unsigned short u) {
  return __uint_as_float((unsigned)u << 16);
}
__device__ __forceinline__ float bflo(unsigned u) { return __uint_as_float(u << 16); }
__device__ __forceinline__ float bfhi(unsigned u) { return __uint_as_float(u & 0xffff0000u); }
__device__ __forceinline__ unsigned packbf(float f0, float f1) {
  return (unsigned)f2bf(f0) | ((unsigned)f2bf(f1) << 16);
}
__device__ __forceinline__ void gload16(const void* g, void* l) {
  __builtin_amdgcn_global_load_lds((const __attribute__((address_space(1))) void*)g,
                                   (__attribute__((address_space(3))) void*)l, 16, 0, 0);
}

// ---------------- CSR build ----------------
__global__ void k_hist(const int* __restrict__ dst, int* __restrict__ deg, int E) {
  int i = blockIdx.x * 256 + threadIdx.x;
  if (i < E) atomicAdd(&deg[dst[i]], 1);
}

__global__ __launch_bounds__(1024)
void k_scan(const int* __restrict__ deg, int* __restrict__ rp, int* __restrict__ cur, int Nn) {
  __shared__ int part[1024];
  int t = threadIdx.x;
  int chunk = (Nn + 1023) >> 10;
  int s0 = t * chunk;
  int e0 = s0 + chunk; if (e0 > Nn) e0 = Nn;
  int s = 0;
  for (int i = s0; i < e0; ++i) s += deg[i];
  part[t] = s;
  __syncthreads();
  for (int off = 1; off < 1024; off <<= 1) {
    int v = (t >= off) ? part[t - off] : 0;
    __syncthreads();
    part[t] += v;
    __syncthreads();
  }
  int base = (t == 0) ? 0 : part[t - 1];
  for (int i = s0; i < e0; ++i) {
    rp[i] = base; cur[i] = base; base += deg[i];
  }
  if (t == 0) rp[Nn] = part[1023];
}

__global__ void k_fill(const int* __restrict__ src, const int* __restrict__ dst,
                       int* __restrict__ cur, int* __restrict__ srcs, int E) {
  int i = blockIdx.x * 256 + threadIdx.x;
  if (i < E) {
    int p = atomicAdd(&cur[dst[i]], 1);
    srcs[p] = src[i];
  }
}

// ---------------- weight transpose fp32 [K,N] -> bf16 [N,K] ----------------
__global__ void k_wT(const float* __restrict__ W, unsigned short* __restrict__ Wt, int K, int Nc) {
  int idx = blockIdx.x * 256 + threadIdx.x;
  if (idx >= K * Nc) return;
  int k = idx % K, n = idx / K;                       // k fastest -> coalesced writes
  Wt[(size_t)n * K + k] = f2bf(W[(size_t)k * Nc + n]);
}

__global__ void k_cast(const float* __restrict__ src, unsigned short* __restrict__ dst, int n) {
  int i = blockIdx.x * 256 + threadIdx.x;
  if (i < n) dst[i] = f2bf(src[i]);
}

// ---------------- bf16 MFMA GEMM, 256x256 tile, BK=64, 8 waves, dbuf ----------------
// C = [R +] act(A @ W + bias), A bf16 row-major (dual-source concat along K),
// Wt = W^T bf16 [Nc, Ktot] row-major. fp32 accumulate.
// Waves: 2(M) x 4(N); per-wave output 128x64. LDS 128 KiB (2 buffers).
// Schedule: front-load next tile's 8 global_load_lds, compute current tile in
// 4 register-subtile phases (each LDS fragment read exactly once), 1 barrier/tile.
template<int ACT, bool RES, bool DUAL, bool W32, bool WBF>
__global__ __launch_bounds__(512, 1)
void k_mfma(const unsigned short* __restrict__ A1, const unsigned short* __restrict__ A2,
            int K1, int K2,
            const unsigned short* __restrict__ Wt, const float* __restrict__ bias,
            const float* R, float* C32, unsigned short* Cbf, int M, int Nc) {
  __shared__ unsigned short As[2][256 * 64];   // [buf][row][64] bf16, 128B rows, XOR-swizzled segs
  __shared__ unsigned short Bs[2][256 * 64];
  const int tid = threadIdx.x;
  const int lane = tid & 63, wv = tid >> 6;
  const int wm = wv >> 2, wn = wv & 3;          // wave grid 2x4
  const int m0 = blockIdx.x * 256, n0 = blockIdx.y * 256;
  const int rA = lane & 15, kg = lane >> 4;
  const int Ktot = K1 + K2;
  const int nt = Ktot >> 6;

  f32x4 acc[8][4];
#pragma unroll
  for (int fm = 0; fm < 8; ++fm)
#pragma unroll
    for (int n = 0; n < 4; ++n)
#pragma unroll
      for (int r = 0; r < 4; ++r) acc[fm][n][r] = 0.f;

  // stage K-tile t into buffer b: 2048 16B-chunks per matrix, 4 issues x 512 thr.
  // linear LDS dest; swizzle on the GLOBAL source k-segment (involution, 0 conflicts measured).
  auto stage = [&](int t, int b) {
    int k0 = t << 6;
    const unsigned short* Asrc; int kc, lda;
    if (!DUAL || k0 < K1) { Asrc = A1; kc = k0; lda = K1; }
    else                  { Asrc = A2; kc = k0 - K1; lda = K2; }
#pragma unroll
    for (int is = 0; is < 4; ++is) {
      int chunk = is * 512 + tid;
      int row = chunk >> 3, seg = chunk & 7;
      int ks = seg ^ (row & 7);
      int gm = m0 + row; gm = gm < M ? gm : M - 1;
      gload16(Asrc + (size_t)gm * lda + kc + ks * 8, (char*)As[b] + (size_t)chunk * 16);
      gload16(Wt + (size_t)(n0 + row) * Ktot + k0 + ks * 8, (char*)Bs[b] + (size_t)chunk * 16);
    }
  };

  stage(0, 0);
  __syncthreads();   // compiler emits vmcnt(0) drain before barrier

  for (int t = 0; t < nt; ++t) {
    const int b = t & 1;
    if (t + 1 < nt) stage(t + 1, b ^ 1);   // issue-early: latency hides under 4 phases
#pragma unroll
    for (int kk = 0; kk < 2; ++kk) {
      short8 bfr[4];
#pragma unroll
      for (int n = 0; n < 4; ++n) {
        int col = wn * 64 + n * 16 + rA;
        int ks = (kk * 4 + kg) ^ (col & 7);
        bfr[n] = *reinterpret_cast<const short8*>((const char*)Bs[b] + col * 128 + ks * 16);
      }
#pragma unroll
      for (int mq = 0; mq < 2; ++mq) {
        short8 af[4];
#pragma unroll
        for (int m = 0; m < 4; ++m) {
          int row = wm * 128 + mq * 64 + m * 16 + rA;
          int ks = (kk * 4 + kg) ^ (row & 7);
          af[m] = *reinterpret_cast<const short8*>((const char*)As[b] + row * 128 + ks * 16);
        }
        __builtin_amdgcn_s_setprio(1);
#pragma unroll
        for (int m = 0; m < 4; ++m)
#pragma unroll
          for (int n = 0; n < 4; ++n)
            acc[mq * 4 + m][n] =
                __builtin_amdgcn_mfma_f32_16x16x32_bf16(af[m], bfr[n], acc[mq * 4 + m][n], 0, 0, 0);
        __builtin_amdgcn_s_setprio(0);
      }
    }
    __syncthreads();   // one barrier per K-tile: drains prefetch vmcnt + read/write handoff
  }

  // epilogue: C/D layout col=lane&15, row=(lane>>4)*4+reg
#pragma unroll
  for (int fm = 0; fm < 8; ++fm) {
    int gr0 = m0 + wm * 128 + fm * 16 + kg * 4;
#pragma unroll
    for (int n = 0; n < 4; ++n) {
      int gc = n0 + wn * 64 + n * 16 + rA;
      float bv = bias[gc];
#pragma unroll
      for (int r = 0; r < 4; ++r) {
        int gr = gr0 + r;
        if (gr < M) {
          float v = acc[fm][n][r] + bv;
          if (ACT == 1) v = gelu_exact(v);
          if (RES) v += R[(size_t)gr * Nc + gc];
          if (W32) C32[(size_t)gr * Nc + gc] = v;
          if (WBF) Cbf[(size_t)gr * Nc + gc] = f2bf(v);
        }
      }
    }
  }
}

// ---------------- mean aggregation over bf16 rows (one wave per node) ----------------
template<int W, bool ROT>
__global__ __launch_bounds__(256)
void k_agg(const unsigned short* __restrict__ X, const int* __restrict__ rp,
           const int* __restrict__ srcs, const float* __restrict__ o,
           unsigned short* __restrict__ out, int Nn) {
  int wid = (blockIdx.x * 256 + threadIdx.x) >> 6;
  int lane = threadIdx.x & 63;
  if (wid >= Nn) return;
  constexpr int PE = W / 64;    // bf16 elems per lane: 8 (W=512) or 4 (W=256)
  float a[PE];
#pragma unroll
  for (int p = 0; p < PE; ++p) a[p] = 0.f;
  int beg = rp[wid], end = rp[wid + 1];
  for (int e = beg; e < end; ++e) {
    int s = srcs[e];
    const unsigned* row = reinterpret_cast<const unsigned*>(X + (size_t)s * W) + lane * (PE / 2);
    if (PE == 8) {
      uint4 v = *reinterpret_cast<const uint4*>(row);
      a[0] += bflo(v.x); a[1] += bfhi(v.x); a[2] += bflo(v.y); a[3] += bfhi(v.y);
      a[4] += bflo(v.z); a[5] += bfhi(v.z); a[6] += bflo(v.w); a[7] += bfhi(v.w);
    } else {
      uint2 v = *reinterpret_cast<const uint2*>(row);
      a[0] += bflo(v.x); a[1] += bfhi(v.x); a[2] += bflo(v.y); a[3] += bfhi(v.y);
    }
  }
  float inv = (end > beg) ? 1.0f / (float)(end - beg) : 0.0f;
#pragma unroll
  for (int p = 0; p < PE; ++p) a[p] *= inv;
  if (ROT) {
    float4 oc = *reinterpret_cast<const float4*>(o + (size_t)wid * 256 + lane * 4); // c0,s0,c1,s1
    float m0 = oc.x * a[0] - oc.y * a[1];
    float m1 = oc.y * a[0] + oc.x * a[1];
    float m2 = oc.z * a[2] - oc.w * a[3];
    float m3 = oc.w * a[2] + oc.z * a[3];
    a[0] = m0; a[1] = m1; a[2] = m2; a[3] = m3;
  }
  unsigned short* op = out + (size_t)wid * W + lane * PE;
  if (PE == 8) {
    uint4 rv;
    rv.x = packbf(a[0], a[1]); rv.y = packbf(a[2], a[3]);
    rv.z = packbf(a[4], a[5]); rv.w = packbf(a[6], a[7]);
    *reinterpret_cast<uint4*>(op) = rv;
  } else {
    uint2 rv;
    rv.x = packbf(a[0], a[1]); rv.y = packbf(a[2], a[3]);
    *reinterpret_cast<uint2*>(op) = rv;
  }
}

// ---------------- Householder(2x2) -> rotation params (nr is bf16) ----------------
__global__ void k_oparams(const unsigned short* __restrict__ nr, float* __restrict__ o, int total) {
  int idx = blockIdx.x * 256 + threadIdx.x;
  if (idx >= total) return;
  float x = bf2f(nr[(size_t)idx * 4 + 2]);
  float inv = 1.0f / (1.0f + x * x);
  o[(size_t)idx * 2]     = (x * x - 1.0f) * inv;
  o[(size_t)idx * 2 + 1] = 2.0f * x * inv;
}

// ---------------- LayerNorm + rotate-into-frame; bf16 outputs ----------------
__global__ __launch_bounds__(256)
void k_ln_rot(const float* __restrict__ h, const float* __restrict__ o,
              const float* __restrict__ g, const float* __restrict__ b,
              unsigned short* __restrict__ hn, unsigned short* __restrict__ y, int Nn) {
  int wid = (blockIdx.x * 256 + threadIdx.x) >> 6;
  int lane = threadIdx.x & 63;
  if (wid >= Nn) return;
  float4 v = reinterpret_cast<const float4*>(h + (size_t)wid * 256)[lane];
  float s = v.x + v.y + v.z + v.w;
  float ss = v.x * v.x + v.y * v.y + v.z * v.z + v.w * v.w;
#pragma unroll
  for (int off = 1; off < 64; off <<= 1) { s += __shfl_xor(s, off); ss += __shfl_xor(ss, off); }
  float mean = s * (1.0f / 256.0f);
  float var = ss * (1.0f / 256.0f) - mean * mean;
  float rs = rsqrtf(var + 1e-5f);
  float4 gg = reinterpret_cast<const float4*>(g)[lane];
  float4 bb = reinterpret_cast<const float4*>(b)[lane];
  float h0 = (v.x - mean) * rs * gg.x + bb.x;
  float h1 = (v.y - mean) * rs * gg.y + bb.y;
  float h2 = (v.z - mean) * rs * gg.z + bb.z;
  float h3 = (v.w - mean) * rs * gg.w + bb.w;
  uint2 hv; hv.x = packbf(h0, h1); hv.y = packbf(h2, h3);
  *reinterpret_cast<uint2*>(hn + (size_t)wid * 256 + lane * 4) = hv;
  float4 oc = *reinterpret_cast<const float4*>(o + (size_t)wid * 256 + lane * 4); // c0,s0,c1,s1
  float y0 =  oc.x * h0 + oc.y * h1;
  float y1 = -oc.y * h0 + oc.x * h1;
  float y2 =  oc.z * h2 + oc.w * h3;
  float y3 = -oc.w * h2 + oc.z * h3;
  uint2 yv; yv.x = packbf(y0, y1); yv.y = packbf(y2, y3);
  *reinterpret_cast<uint2*>(y + (size_t)wid * 256 + lane * 4) = yv;
}

// ---------------- final: out = LN(h) @ w_out + b_out ----------------
__global__ __launch_bounds__(256)
void k_final(const float* __restrict__ h, const float* __restrict__ g,
             const float* __restrict__ b, const float* __restrict__ wout,
             const float* __restrict__ bout, float* __restrict__ out, int Nn) {
  int wid = (blockIdx.x * 256 + threadIdx.x) >> 6;
  int lane = threadIdx.x & 63;
  if (wid >= Nn) return;
  float4 v = reinterpret_cast<const float4*>(h + (size_t)wid * 256)[lane];
  float s = v.x + v.y + v.z + v.w;
  float ss = v.x * v.x + v.y * v.y + v.z * v.z + v.w * v.w;
#pragma unroll
  for (int off = 1; off < 64; off <<= 1) { s += __shfl_xor(s, off); ss += __shfl_xor(ss, off); }
  float mean = s * (1.0f / 256.0f);
  float var = ss * (1.0f / 256.0f) - mean * mean;
  float rs = rsqrtf(var + 1e-5f);
  float4 gg = reinterpret_cast<const float4*>(g)[lane];
  float4 bb = reinterpret_cast<const float4*>(b)[lane];
  float hv[4];
  hv[0] = (v.x - mean) * rs * gg.x + bb.x;
  hv[1] = (v.y - mean) * rs * gg.y + bb.y;
  hv[2] = (v.z - mean) * rs * gg.z + bb.z;
  hv[3] = (v.w - mean) * rs * gg.w + bb.w;
  int c0 = lane * 4;
  float dots[5];
#pragma unroll
  for (int j = 0; j < 5; ++j) {
    float p = hv[0] * wout[(size_t)(c0 + 0) * 5 + j] + hv[1] * wout[(size_t)(c0 + 1) * 5 + j]
            + hv[2] * wout[(size_t)(c0 + 2) * 5 + j] + hv[3] * wout[(size_t)(c0 + 3) * 5 + j];
#pragma unroll
    for (int off = 1; off < 64; off <<= 1) p += __shfl_xor(p, off);
    dots[j] = p;
  }
  if (lane == 0) {
#pragma unroll
    for (int j = 0; j < 5; ++j) out[(size_t)wid * 5 + j] = dots[j] + bout[j];
  }
}

// ---------------- host-side launch ----------------
extern "C" void kernel_launch(void* const* d_in, const int* in_sizes, int n_in,
                              void* d_out, int out_size, void* d_ws, size_t ws_size,
                              hipStream_t stream) {
  const float* x       = (const float*)d_in[0];
  const int*   ei      = (const int*)  d_in[1];
  const float* w_in    = (const float*)d_in[2];
  const float* b_in    = (const float*)d_in[3];
  const float* se_in_w = (const float*)d_in[4];
  const float* se_in_b = (const float*)d_in[5];
  const float* sage_w1 = (const float*)d_in[6];
  const float* sage_b1 = (const float*)d_in[7];
  const float* sage_w2 = (const float*)d_in[8];
  const float* sage_b2 = (const float*)d_in[9];
  const float* se_out_w= (const float*)d_in[10];
  const float* se_out_b= (const float*)d_in[11];
  const float* enc_w1  = (const float*)d_in[12];
  const float* enc_b1  = (const float*)d_in[13];
  const float* enc_w2  = (const float*)d_in[14];
  const float* enc_b2  = (const float*)d_in[15];
  const float* ln_g    = (const float*)d_in[16];
  const float* ln_b    = (const float*)d_in[17];
  const float* bdl_w1  = (const float*)d_in[18];
  const float* bdl_b1  = (const float*)d_in[19];
  const float* bdl_w2  = (const float*)d_in[20];
  const float* bdl_b2  = (const float*)d_in[21];
  const float* oln_g   = (const float*)d_in[22];
  const float* oln_b   = (const float*)d_in[23];
  const float* w_out   = (const float*)d_in[24];
  const float* b_out   = (const float*)d_in[25];
  float* out = (float*)d_out;

  const int HID = 256, SW = 512;
  const int N = in_sizes[0] / HID;   // 30000
  const int E = in_sizes[1] / 2;     // 480000

  // ---- workspace layout (~244 MB) ----
  float* ws = (float*)d_ws;
  float* h32 = ws;                              // [N,256] fp32 residual carrier
  float* z32 = h32 + (size_t)N * HID;           // [N,512] fp32 residual carrier
  float* o   = z32 + (size_t)N * SW;            // [N,256] rotation (c,s)*128
  unsigned short* h_bf = (unsigned short*)(o + (size_t)N * HID);  // [N,256]
  unsigned short* z_bf = h_bf + (size_t)N * HID;                  // [N,512]
  unsigned short* t_bf = z_bf + (size_t)N * SW;                   // [N,512]
  unsigned short* u_bf = t_bf + (size_t)N * SW;                   // [N,512]
  // weight transposes (bf16 [N,K])
  unsigned short* wts = u_bf + (size_t)N * SW;
  size_t off = 0;
  unsigned short* wt_in    = wts + off; off += 256 * 256;
  unsigned short* wt_se_in = wts + off; off += 512 * 256;
  unsigned short* wt_sage1 = wts + off; off += (size_t)5 * 512 * 1024;
  unsigned short* wt_sage2 = wts + off; off += (size_t)5 * 512 * 512;
  unsigned short* wt_se_out= wts + off; off += 512 * 512;
  unsigned short* wt_enc1  = wts + off; off += (size_t)2 * 512 * 512;
  unsigned short* wt_enc2  = wts + off; off += (size_t)2 * 512 * 512;
  unsigned short* wt_bdl1  = wts + off; off += (size_t)2 * 256 * 512;
  unsigned short* wt_bdl2  = wts + off; off += (size_t)2 * 256 * 256;
  int* deg  = (int*)(wts + off);
  int* rp   = deg + N;
  int* cur  = rp + N + 1;
  int* srcs = cur + N;
  size_t need = (size_t)((char*)(srcs + E) - (char*)d_ws);
  if (ws_size < need) return;

  // aliases (lifetime-disjoint)
  unsigned short* xbf = u_bf;                   // x cast, consumed by first GEMM
  unsigned short* hn  = z_bf;                   // after encoder done, z free
  unsigned short* y   = z_bf + (size_t)N * HID;
  unsigned short* msg = t_bf;                   // nr consumed by k_oparams first
  unsigned short* g2  = u_bf;

  const int* esrc = ei;
  const int* edst = ei + E;

  auto cdiv = [](int a, int b) { return (a + b - 1) / b; };
  dim3 blk(256);
  dim3 blk512(512);
  int gm_blocks = cdiv(N, 256);                 // 118
  dim3 g_g256(gm_blocks, 1);   // Nc=256
  dim3 g_g512(gm_blocks, 2);   // Nc=512
  int gw = cdiv(N * 64, 256);

  // ---- CSR build ----
  hipMemsetAsync(deg, 0, sizeof(int) * N, stream);
  k_hist<<<cdiv(E, 256), blk, 0, stream>>>(edst, deg, E);
  k_scan<<<1, 1024, 0, stream>>>(deg, rp, cur, N);
  k_fill<<<cdiv(E, 256), blk, 0, stream>>>(esrc, edst, cur, srcs, E);

  // ---- weight transposes to bf16 ----
  auto wT = [&](const float* W, unsigned short* Wt, int K, int Nc) {
    k_wT<<<cdiv(K * Nc, 256), blk, 0, stream>>>(W, Wt, K, Nc);
  };
  wT(w_in, wt_in, 256, 256);
  wT(se_in_w, wt_se_in, 256, 512);
  for (int i = 0; i < 5; ++i) {
    wT(sage_w1 + (size_t)i * 1024 * 512, wt_sage1 + (size_t)i * 512 * 1024, 1024, 512);
    wT(sage_w2 + (size_t)i * 512 * 512,  wt_sage2 + (size_t)i * 512 * 512,  512, 512);
  }
  wT(se_out_w, wt_se_out, 512, 512);
  for (int k = 0; k < 2; ++k) {
    wT(enc_w1 + (size_t)k * 512 * 512, wt_enc1 + (size_t)k * 512 * 512, 512, 512);
    wT(enc_w2 + (size_t)k * 512 * 512, wt_enc2 + (size_t)k * 512 * 512, 512, 512);
    wT(bdl_w1 + (size_t)k * 512 * 256, wt_bdl1 + (size_t)k * 256 * 512, 512, 256);
    wT(bdl_w2 + (size_t)k * 256 * 256, wt_bdl2 + (size_t)k * 256 * 256, 256, 256);
  }
  k_cast<<<cdiv(N * HID, 256), blk, 0, stream>>>(x, xbf, N * HID);

  // ---- h = gelu(x @ w_in + b_in) : fp32 + bf16 ----
  k_mfma<1, false, false, true, true><<<g_g256, blk512, 0, stream>>>(
      xbf, nullptr, 256, 0, wt_in, b_in, nullptr, h32, h_bf, N, 256);

  for (int k = 0; k < 2; ++k) {
    // z = gelu(h @ se_in_w + b) : fp32 + bf16
    k_mfma<1, false, false, true, true><<<g_g512, blk512, 0, stream>>>(
        h_bf, nullptr, 256, 0, wt_se_in, se_in_b, nullptr, z32, z_bf, N, 512);
    for (int i = 0; i < 5; ++i) {
      k_agg<512, false><<<gw, blk, 0, stream>>>(z_bf, rp, srcs, nullptr, t_bf, N);
      k_mfma<1, false, true, false, true><<<g_g512, blk512, 0, stream>>>(
          z_bf, t_bf, 512, 512, wt_sage1 + (size_t)i * 512 * 1024,
          sage_b1 + (size_t)i * SW, nullptr, nullptr, u_bf, N, 512);
      k_mfma<0, true, false, true, true><<<g_g512, blk512, 0, stream>>>(
          u_bf, nullptr, 512, 0, wt_sage2 + (size_t)i * 512 * 512,
          sage_b2 + (size_t)i * SW, z32, z32, z_bf, N, 512);
    }
    // enc = z @ se_out_w + b   (bf16 only)
    k_mfma<0, false, false, false, true><<<g_g512, blk512, 0, stream>>>(
        z_bf, nullptr, 512, 0, wt_se_out, se_out_b, nullptr, nullptr, t_bf, N, 512);
    // nr = gelu(enc @ enc_w1 + b) @ enc_w2 + b
    k_mfma<1, false, false, false, true><<<g_g512, blk512, 0, stream>>>(
        t_bf, nullptr, 512, 0, wt_enc1 + (size_t)k * 512 * 512,
        enc_b1 + (size_t)k * SW, nullptr, nullptr, u_bf, N, 512);
    k_mfma<0, false, false, false, true><<<g_g512, blk512, 0, stream>>>(
        u_bf, nullptr, 512, 0, wt_enc2 + (size_t)k * 512 * 512,
        enc_b2 + (size_t)k * SW, nullptr, nullptr, t_bf, N, 512);
    // rotation params; hn=LN(h), y=O@hn; msg=O^T@mean(y)
    k_oparams<<<cdiv(N * 128, 256), blk, 0, stream>>>(t_bf, o, N * 128);
    k_ln_rot<<<gw, blk, 0, stream>>>(h32, o, ln_g + (size_t)k * HID, ln_b + (size_t)k * HID, hn, y, N);
    k_agg<256, true><<<gw, blk, 0, stream>>>(y, rp, srcs, o, msg, N);
    // h = h + gelu([hn|msg] @ bdl_w1 + b1) @ bdl_w2 + b2
    k_mfma<1, false, true, false, true><<<g_g256, blk512, 0, stream>>>(
        hn, msg, 256, 256, wt_bdl1 + (size_t)k * 256 * 512,
        bdl_b1 + (size_t)k * HID, nullptr, nullptr, g2, N, 256);
    k_mfma<0, true, false, true, true><<<g_g256, blk512, 0, stream>>>(
        g2, nullptr, 256, 0, wt_bdl2 + (size_t)k * 256 * 256,
        bdl_b2 + (size_t)k * HID, h32, h32, h_bf, N, 256);
  }

  k_final<<<gw, blk, 0, stream>>>(h32, oln_g, oln_b, w_out, b_out, out, N);
}

// Round 4
// 2746.652 us; speedup vs baseline: 3.5941x; 1.0373x over previous
//
#include <hip/hip_runtime.h>
#include <hip/hip_bf16.h>
#include <cstdint>
#include <cstddef>

// N=30000 nodes, E=480000 edges, HID=256, SW=512, NB=128 bundles of dim 2.
// Householder(2x2) collapses to planar rotation: x=X[1,0]; c=(x^2-1)/(1+x^2), s=2x/(1+x^2).

typedef __attribute__((ext_vector_type(8))) short short8;
typedef __attribute__((ext_vector_type(4))) float f32x4;

__device__ __forceinline__ float gelu_exact(float x) {
  return 0.5f * x * (1.0f + erff(x * 0.7071067811865475f));
}
__device__ __forceinline__ unsigned short f2bf(float f) {
  __hip_bfloat16 b = __float2bfloat16(f);
  return *reinterpret_cast<unsigned short*>(&b);
}
__device__ __forceinline__ float bf2f(unsigned short u) {
  return __uint_as_float((unsigned)u << 16);
}
__device__ __forceinline__ float bflo(unsigned u) { return __uint_as_float(u << 16); }
__device__ __forceinline__ float bfhi(unsigned u) { return __uint_as_float(u & 0xffff0000u); }
__device__ __forceinline__ unsigned packbf(float f0, float f1) {
  return (unsigned)f2bf(f0) | ((unsigned)f2bf(f1) << 16);
}
__device__ __forceinline__ void gload16(const void* g, void* l) {
  __builtin_amdgcn_global_load_lds((const __attribute__((address_space(1))) void*)g,
                                   (__attribute__((address_space(3))) void*)l, 16, 0, 0);
}
#define SCHEDB() __builtin_amdgcn_sched_barrier(0)

// ---------------- CSR build ----------------
__global__ void k_hist(const int* __restrict__ dst, int* __restrict__ deg, int E) {
  int i = blockIdx.x * 256 + threadIdx.x;
  if (i < E) atomicAdd(&deg[dst[i]], 1);
}

__global__ __launch_bounds__(1024)
void k_scan(const int* __restrict__ deg, int* __restrict__ rp, int* __restrict__ cur, int Nn) {
  __shared__ int part[1024];
  int t = threadIdx.x;
  int chunk = (Nn + 1023) >> 10;
  int s0 = t * chunk;
  int e0 = s0 + chunk; if (e0 > Nn) e0 = Nn;
  int s = 0;
  for (int i = s0; i < e0; ++i) s += deg[i];
  part[t] = s;
  __syncthreads();
  for (int off = 1; off < 1024; off <<= 1) {
    int v = (t >= off) ? part[t - off] : 0;
    __syncthreads();
    part[t] += v;
    __syncthreads();
  }
  int base = (t == 0) ? 0 : part[t - 1];
  for (int i = s0; i < e0; ++i) {
    rp[i] = base; cur[i] = base; base += deg[i];
  }
  if (t == 0) rp[Nn] = part[1023];
}

__global__ void k_fill(const int* __restrict__ src, const int* __restrict__ dst,
                       int* __restrict__ cur, int* __restrict__ srcs, int E) {
  int i = blockIdx.x * 256 + threadIdx.x;
  if (i < E) {
    int p = atomicAdd(&cur[dst[i]], 1);
    srcs[p] = src[i];
  }
}

// ---------------- batched weight transpose fp32 [K,N] -> bf16 [N,K] ----------------
__global__ void k_wT(const float* __restrict__ W, unsigned short* __restrict__ Wt, int K, int Nc) {
  const float* Ws = W + (size_t)blockIdx.y * K * Nc;
  unsigned short* Wd = Wt + (size_t)blockIdx.y * K * Nc;
  int idx = blockIdx.x * 256 + threadIdx.x;
  if (idx >= K * Nc) return;
  int k = idx % K, n = idx / K;                       // k fastest -> coalesced writes
  Wd[(size_t)n * K + k] = f2bf(Ws[(size_t)k * Nc + n]);
}

__global__ void k_cast(const float* __restrict__ src, unsigned short* __restrict__ dst, int n) {
  int i = blockIdx.x * 256 + threadIdx.x;
  if (i < n) dst[i] = f2bf(src[i]);
}

// ---------------- bf16 MFMA GEMM, MBx256 tile, BK=64, 8 waves ----------------
// C = [R +] act(A @ W + bias), A bf16 row-major (dual-source concat along K),
// Wt = W^T bf16 [Nc, Ktot] row-major. fp32 accumulate.
// Depth-2 counted-vmcnt pipeline: per K-tile
//   vmcnt(LOADS) ; s_barrier          -> tile t staged & visible
//   ds_read all fragments ; lgkmcnt(0); s_barrier -> buffer free
//   stage(t+2) into freed buffer       (DMA overlaps MFMA)
//   64 (or 32) MFMA from registers
// No vmcnt(0) in steady state; LOADS = own in-flight loads of the NEXT tile.
template<int MB, int ACT, bool RES, bool DUAL, bool W32, bool WBF>
__global__ __launch_bounds__(512, 2)
void k_mfma(const unsigned short* __restrict__ A1, const unsigned short* __restrict__ A2,
            int K1, int K2,
            const unsigned short* __restrict__ Wt, const float* __restrict__ bias,
            const float* R, float* C32, unsigned short* Cbf, int M, int Nc) {
  constexpr int MQ = MB / 128;              // 2 (MB=256) or 1 (MB=128)
  constexpr int LOADS = MB / 64 + 4;        // gload16 per thread per stage: 8 or 6
  __shared__ unsigned short As[2][MB * 64];   // 128B rows, XOR-swizzled segs
  __shared__ unsigned short Bs[2][256 * 64];
  const int tid = threadIdx.x;
  const int lane = tid & 63, wv = tid >> 6;
  const int wm = wv >> 2, wn = wv & 3;          // wave grid 2x4
  const int m0 = blockIdx.x * MB, n0 = blockIdx.y * 256;
  const int rA = lane & 15, kg = lane >> 4;
  const int Ktot = K1 + K2;
  const int nt = Ktot >> 6;

  f32x4 acc[MQ * 4][4];
#pragma unroll
  for (int f = 0; f < MQ * 4; ++f)
#pragma unroll
    for (int n = 0; n < 4; ++n)
#pragma unroll
      for (int r = 0; r < 4; ++r) acc[f][n][r] = 0.f;

  // stage K-tile t into buffer b. Linear LDS dest; swizzle on the GLOBAL source
  // k-segment (involution; 0 bank conflicts measured).
  auto stage = [&](int t, int b) {
    int k0 = t << 6;
    const unsigned short* Asrc; int kc, lda;
    if (!DUAL || k0 < K1) { Asrc = A1; kc = k0; lda = K1; }
    else                  { Asrc = A2; kc = k0 - K1; lda = K2; }
#pragma unroll
    for (int is = 0; is < MB / 64; ++is) {
      int chunk = is * 512 + tid;
      int row = chunk >> 3, seg = chunk & 7;
      int ks = seg ^ (row & 7);
      int gm = m0 + row; gm = gm < M ? gm : M - 1;
      gload16(Asrc + (size_t)gm * lda + kc + ks * 8, (char*)As[b] + (size_t)chunk * 16);
    }
#pragma unroll
    for (int is = 0; is < 4; ++is) {
      int chunk = is * 512 + tid;
      int row = chunk >> 3, seg = chunk & 7;
      int ks = seg ^ (row & 7);
      gload16(Wt + (size_t)(n0 + row) * Ktot + k0 + ks * 8, (char*)Bs[b] + (size_t)chunk * 16);
    }
  };

  stage(0, 0);
  if (nt > 1) stage(1, 1);

  for (int t = 0; t < nt; ++t) {
    const int b = t & 1;
    // tile t ready: own loads for t complete (t+1's LOADS may stay in flight)
    if (t < nt - 1) {
      if constexpr (LOADS == 8) asm volatile("s_waitcnt vmcnt(8)" ::: "memory");
      else                      asm volatile("s_waitcnt vmcnt(6)" ::: "memory");
    } else {
      asm volatile("s_waitcnt vmcnt(0)" ::: "memory");
    }
    SCHEDB();
    __builtin_amdgcn_s_barrier();
    SCHEDB();

    short8 bfrag[2][4], afrag[2][MQ * 4];
#pragma unroll
    for (int kk = 0; kk < 2; ++kk)
#pragma unroll
      for (int n = 0; n < 4; ++n) {
        int col = wn * 64 + n * 16 + rA;
        int ks = (kk * 4 + kg) ^ (col & 7);
        bfrag[kk][n] = *reinterpret_cast<const short8*>((const char*)Bs[b] + col * 128 + ks * 16);
      }
#pragma unroll
    for (int kk = 0; kk < 2; ++kk)
#pragma unroll
      for (int mq = 0; mq < MQ; ++mq)
#pragma unroll
        for (int m = 0; m < 4; ++m) {
          int row = wm * (MB / 2) + mq * 64 + m * 16 + rA;
          int ks = (kk * 4 + kg) ^ (row & 7);
          afrag[kk][mq * 4 + m] =
              *reinterpret_cast<const short8*>((const char*)As[b] + row * 128 + ks * 16);
        }
    asm volatile("s_waitcnt lgkmcnt(0)" ::: "memory");
    SCHEDB();
    __builtin_amdgcn_s_barrier();   // all waves done reading buf b
    SCHEDB();
    if (t + 2 < nt) stage(t + 2, b);  // DMA into freed buffer, overlaps MFMA

    __builtin_amdgcn_s_setprio(1);
#pragma unroll
    for (int kk = 0; kk < 2; ++kk)
#pragma unroll
      for (int f = 0; f < MQ * 4; ++f)
#pragma unroll
        for (int n = 0; n < 4; ++n)
          acc[f][n] = __builtin_amdgcn_mfma_f32_16x16x32_bf16(afrag[kk][f], bfrag[kk][n],
                                                              acc[f][n], 0, 0, 0);
    __builtin_amdgcn_s_setprio(0);
  }

  // epilogue: C/D layout col=lane&15, row=(lane>>4)*4+reg
#pragma unroll
  for (int f = 0; f < MQ * 4; ++f) {
    int gr0 = m0 + wm * (MB / 2) + f * 16 + kg * 4;
#pragma unroll
    for (int n = 0; n < 4; ++n) {
      int gc = n0 + wn * 64 + n * 16 + rA;
      float bv = bias[gc];
#pragma unroll
      for (int r = 0; r < 4; ++r) {
        int gr = gr0 + r;
        if (gr < M) {
          float v = acc[f][n][r] + bv;
          if (ACT == 1) v = gelu_exact(v);
          if (RES) v += R[(size_t)gr * Nc + gc];
          if (W32) C32[(size_t)gr * Nc + gc] = v;
          if (WBF) Cbf[(size_t)gr * Nc + gc] = f2bf(v);
        }
      }
    }
  }
}

// ---------------- mean aggregation over bf16 rows (one wave per node) ----------------
template<int W, bool ROT>
__global__ __launch_bounds__(256)
void k_agg(const unsigned short* __restrict__ X, const int* __restrict__ rp,
           const int* __restrict__ srcs, const float* __restrict__ o,
           unsigned short* __restrict__ out, int Nn) {
  int wid = (blockIdx.x * 256 + threadIdx.x) >> 6;
  int lane = threadIdx.x & 63;
  if (wid >= Nn) return;
  constexpr int PE = W / 64;    // bf16 elems per lane: 8 (W=512) or 4 (W=256)
  float a[PE];
#pragma unroll
  for (int p = 0; p < PE; ++p) a[p] = 0.f;
  int beg = rp[wid], end = rp[wid + 1];
  for (int e = beg; e < end; ++e) {
    int s = srcs[e];
    const unsigned* row = reinterpret_cast<const unsigned*>(X + (size_t)s * W) + lane * (PE / 2);
    if (PE == 8) {
      uint4 v = *reinterpret_cast<const uint4*>(row);
      a[0] += bflo(v.x); a[1] += bfhi(v.x); a[2] += bflo(v.y); a[3] += bfhi(v.y);
      a[4] += bflo(v.z); a[5] += bfhi(v.z); a[6] += bflo(v.w); a[7] += bfhi(v.w);
    } else {
      uint2 v = *reinterpret_cast<const uint2*>(row);
      a[0] += bflo(v.x); a[1] += bfhi(v.x); a[2] += bflo(v.y); a[3] += bfhi(v.y);
    }
  }
  float inv = (end > beg) ? 1.0f / (float)(end - beg) : 0.0f;
#pragma unroll
  for (int p = 0; p < PE; ++p) a[p] *= inv;
  if (ROT) {
    float4 oc = *reinterpret_cast<const float4*>(o + (size_t)wid * 256 + lane * 4); // c0,s0,c1,s1
    float m0 = oc.x * a[0] - oc.y * a[1];
    float m1 = oc.y * a[0] + oc.x * a[1];
    float m2 = oc.z * a[2] - oc.w * a[3];
    float m3 = oc.w * a[2] + oc.z * a[3];
    a[0] = m0; a[1] = m1; a[2] = m2; a[3] = m3;
  }
  unsigned short* op = out + (size_t)wid * W + lane * PE;
  if (PE == 8) {
    uint4 rv;
    rv.x = packbf(a[0], a[1]); rv.y = packbf(a[2], a[3]);
    rv.z = packbf(a[4], a[5]); rv.w = packbf(a[6], a[7]);
    *reinterpret_cast<uint4*>(op) = rv;
  } else {
    uint2 rv;
    rv.x = packbf(a[0], a[1]); rv.y = packbf(a[2], a[3]);
    *reinterpret_cast<uint2*>(op) = rv;
  }
}

// ---------------- Householder(2x2) -> rotation params (nr is bf16) ----------------
__global__ void k_oparams(const unsigned short* __restrict__ nr, float* __restrict__ o, int total) {
  int idx = blockIdx.x * 256 + threadIdx.x;
  if (idx >= total) return;
  float x = bf2f(nr[(size_t)idx * 4 + 2]);
  float inv = 1.0f / (1.0f + x * x);
  o[(size_t)idx * 2]     = (x * x - 1.0f) * inv;
  o[(size_t)idx * 2 + 1] = 2.0f * x * inv;
}

// ---------------- LayerNorm + rotate-into-frame; bf16 outputs ----------------
__global__ __launch_bounds__(256)
void k_ln_rot(const float* __restrict__ h, const float* __restrict__ o,
              const float* __restrict__ g, const float* __restrict__ b,
              unsigned short* __restrict__ hn, unsigned short* __restrict__ y, int Nn) {
  int wid = (blockIdx.x * 256 + threadIdx.x) >> 6;
  int lane = threadIdx.x & 63;
  if (wid >= Nn) return;
  float4 v = reinterpret_cast<const float4*>(h + (size_t)wid * 256)[lane];
  float s = v.x + v.y + v.z + v.w;
  float ss = v.x * v.x + v.y * v.y + v.z * v.z + v.w * v.w;
#pragma unroll
  for (int off = 1; off < 64; off <<= 1) { s += __shfl_xor(s, off); ss += __shfl_xor(ss, off); }
  float mean = s * (1.0f / 256.0f);
  float var = ss * (1.0f / 256.0f) - mean * mean;
  float rs = rsqrtf(var + 1e-5f);
  float4 gg = reinterpret_cast<const float4*>(g)[lane];
  float4 bb = reinterpret_cast<const float4*>(b)[lane];
  float h0 = (v.x - mean) * rs * gg.x + bb.x;
  float h1 = (v.y - mean) * rs * gg.y + bb.y;
  float h2 = (v.z - mean) * rs * gg.z + bb.z;
  float h3 = (v.w - mean) * rs * gg.w + bb.w;
  uint2 hv; hv.x = packbf(h0, h1); hv.y = packbf(h2, h3);
  *reinterpret_cast<uint2*>(hn + (size_t)wid * 256 + lane * 4) = hv;
  float4 oc = *reinterpret_cast<const float4*>(o + (size_t)wid * 256 + lane * 4); // c0,s0,c1,s1
  float y0 =  oc.x * h0 + oc.y * h1;
  float y1 = -oc.y * h0 + oc.x * h1;
  float y2 =  oc.z * h2 + oc.w * h3;
  float y3 = -oc.w * h2 + oc.z * h3;
  uint2 yv; yv.x = packbf(y0, y1); yv.y = packbf(y2, y3);
  *reinterpret_cast<uint2*>(y + (size_t)wid * 256 + lane * 4) = yv;
}

// ---------------- final: out = LN(h) @ w_out + b_out ----------------
__global__ __launch_bounds__(256)
void k_final(const float* __restrict__ h, const float* __restrict__ g,
             const float* __restrict__ b, const float* __restrict__ wout,
             const float* __restrict__ bout, float* __restrict__ out, int Nn) {
  int wid = (blockIdx.x * 256 + threadIdx.x) >> 6;
  int lane = threadIdx.x & 63;
  if (wid >= Nn) return;
  float4 v = reinterpret_cast<const float4*>(h + (size_t)wid * 256)[lane];
  float s = v.x + v.y + v.z + v.w;
  float ss = v.x * v.x + v.y * v.y + v.z * v.z + v.w * v.w;
#pragma unroll
  for (int off = 1; off < 64; off <<= 1) { s += __shfl_xor(s, off); ss += __shfl_xor(ss, off); }
  float mean = s * (1.0f / 256.0f);
  float var = ss * (1.0f / 256.0f) - mean * mean;
  float rs = rsqrtf(var + 1e-5f);
  float4 gg = reinterpret_cast<const float4*>(g)[lane];
  float4 bb = reinterpret_cast<const float4*>(b)[lane];
  float hv[4];
  hv[0] = (v.x - mean) * rs * gg.x + bb.x;
  hv[1] = (v.y - mean) * rs * gg.y + bb.y;
  hv[2] = (v.z - mean) * rs * gg.z + bb.z;
  hv[3] = (v.w - mean) * rs * gg.w + bb.w;
  int c0 = lane * 4;
  float dots[5];
#pragma unroll
  for (int j = 0; j < 5; ++j) {
    float p = hv[0] * wout[(size_t)(c0 + 0) * 5 + j] + hv[1] * wout[(size_t)(c0 + 1) * 5 + j]
            + hv[2] * wout[(size_t)(c0 + 2) * 5 + j] + hv[3] * wout[(size_t)(c0 + 3) * 5 + j];
#pragma unroll
    for (int off = 1; off < 64; off <<= 1) p += __shfl_xor(p, off);
    dots[j] = p;
  }
  if (lane == 0) {
#pragma unroll
    for (int j = 0; j < 5; ++j) out[(size_t)wid * 5 + j] = dots[j] + bout[j];
  }
}

// ---------------- host-side launch ----------------
extern "C" void kernel_launch(void* const* d_in, const int* in_sizes, int n_in,
                              void* d_out, int out_size, void* d_ws, size_t ws_size,
                              hipStream_t stream) {
  const float* x       = (const float*)d_in[0];
  const int*   ei      = (const int*)  d_in[1];
  const float* w_in    = (const float*)d_in[2];
  const float* b_in    = (const float*)d_in[3];
  const float* se_in_w = (const float*)d_in[4];
  const float* se_in_b = (const float*)d_in[5];
  const float* sage_w1 = (const float*)d_in[6];
  const float* sage_b1 = (const float*)d_in[7];
  const float* sage_w2 = (const float*)d_in[8];
  const float* sage_b2 = (const float*)d_in[9];
  const float* se_out_w= (const float*)d_in[10];
  const float* se_out_b= (const float*)d_in[11];
  const float* enc_w1  = (const float*)d_in[12];
  const float* enc_b1  = (const float*)d_in[13];
  const float* enc_w2  = (const float*)d_in[14];
  const float* enc_b2  = (const float*)d_in[15];
  const float* ln_g    = (const float*)d_in[16];
  const float* ln_b    = (const float*)d_in[17];
  const float* bdl_w1  = (const float*)d_in[18];
  const float* bdl_b1  = (const float*)d_in[19];
  const float* bdl_w2  = (const float*)d_in[20];
  const float* bdl_b2  = (const float*)d_in[21];
  const float* oln_g   = (const float*)d_in[22];
  const float* oln_b   = (const float*)d_in[23];
  const float* w_out   = (const float*)d_in[24];
  const float* b_out   = (const float*)d_in[25];
  float* out = (float*)d_out;

  const int HID = 256, SW = 512;
  const int N = in_sizes[0] / HID;   // 30000
  const int E = in_sizes[1] / 2;     // 480000

  // ---- workspace layout (~244 MB) ----
  float* ws = (float*)d_ws;
  float* h32 = ws;                              // [N,256] fp32 residual carrier
  float* z32 = h32 + (size_t)N * HID;           // [N,512] fp32 residual carrier
  float* o   = z32 + (size_t)N * SW;            // [N,256] rotation (c,s)*128
  unsigned short* h_bf = (unsigned short*)(o + (size_t)N * HID);  // [N,256]
  unsigned short* z_bf = h_bf + (size_t)N * HID;                  // [N,512]
  unsigned short* t_bf = z_bf + (size_t)N * SW;                   // [N,512]
  unsigned short* u_bf = t_bf + (size_t)N * SW;                   // [N,512]
  // weight transposes (bf16 [N,K])
  unsigned short* wts = u_bf + (size_t)N * SW;
  size_t off = 0;
  unsigned short* wt_in    = wts + off; off += 256 * 256;
  unsigned short* wt_se_in = wts + off; off += 512 * 256;
  unsigned short* wt_sage1 = wts + off; off += (size_t)5 * 512 * 1024;
  unsigned short* wt_sage2 = wts + off; off += (size_t)5 * 512 * 512;
  unsigned short* wt_se_out= wts + off; off += 512 * 512;
  unsigned short* wt_enc1  = wts + off; off += (size_t)2 * 512 * 512;
  unsigned short* wt_enc2  = wts + off; off += (size_t)2 * 512 * 512;
  unsigned short* wt_bdl1  = wts + off; off += (size_t)2 * 256 * 512;
  unsigned short* wt_bdl2  = wts + off; off += (size_t)2 * 256 * 256;
  int* deg  = (int*)(wts + off);
  int* rp   = deg + N;
  int* cur  = rp + N + 1;
  int* srcs = cur + N;
  size_t need = (size_t)((char*)(srcs + E) - (char*)d_ws);
  if (ws_size < need) return;

  // aliases (lifetime-disjoint)
  unsigned short* xbf = u_bf;                   // x cast, consumed by first GEMM
  unsigned short* hn  = z_bf;                   // after encoder done, z free
  unsigned short* y   = z_bf + (size_t)N * HID;
  unsigned short* msg = t_bf;                   // nr consumed by k_oparams first
  unsigned short* g2  = u_bf;

  const int* esrc = ei;
  const int* edst = ei + E;

  auto cdiv = [](int a, int b) { return (a + b - 1) / b; };
  dim3 blk(256);
  dim3 blk512(512);
  dim3 g_g256(cdiv(N, 128), 1);   // Nc=256, MB=128 -> 235 blocks
  dim3 g_g512(cdiv(N, 256), 2);   // Nc=512, MB=256 -> 236 blocks
  int gw = cdiv(N * 64, 256);

  // ---- CSR build ----
  hipMemsetAsync(deg, 0, sizeof(int) * N, stream);
  k_hist<<<cdiv(E, 256), blk, 0, stream>>>(edst, deg, E);
  k_scan<<<1, 1024, 0, stream>>>(deg, rp, cur, N);
  k_fill<<<cdiv(E, 256), blk, 0, stream>>>(esrc, edst, cur, srcs, E);

  // ---- weight transposes to bf16 (batched over blockIdx.y) ----
  auto wT = [&](const float* W, unsigned short* Wt, int K, int Nc, int cnt) {
    k_wT<<<dim3(cdiv(K * Nc, 256), cnt), blk, 0, stream>>>(W, Wt, K, Nc);
  };
  wT(w_in, wt_in, 256, 256, 1);
  wT(se_in_w, wt_se_in, 256, 512, 1);
  wT(sage_w1, wt_sage1, 1024, 512, 5);
  wT(sage_w2, wt_sage2, 512, 512, 5);
  wT(se_out_w, wt_se_out, 512, 512, 1);
  wT(enc_w1, wt_enc1, 512, 512, 2);
  wT(enc_w2, wt_enc2, 512, 512, 2);
  wT(bdl_w1, wt_bdl1, 512, 256, 2);
  wT(bdl_w2, wt_bdl2, 256, 256, 2);
  k_cast<<<cdiv(N * HID, 256), blk, 0, stream>>>(x, xbf, N * HID);

  // ---- h = gelu(x @ w_in + b_in) : fp32 + bf16 ----
  k_mfma<128, 1, false, false, true, true><<<g_g256, blk512, 0, stream>>>(
      xbf, nullptr, 256, 0, wt_in, b_in, nullptr, h32, h_bf, N, 256);

  for (int k = 0; k < 2; ++k) {
    // z = gelu(h @ se_in_w + b) : fp32 + bf16
    k_mfma<256, 1, false, false, true, true><<<g_g512, blk512, 0, stream>>>(
        h_bf, nullptr, 256, 0, wt_se_in, se_in_b, nullptr, z32, z_bf, N, 512);
    for (int i = 0; i < 5; ++i) {
      k_agg<512, false><<<gw, blk, 0, stream>>>(z_bf, rp, srcs, nullptr, t_bf, N);
      k_mfma<256, 1, false, true, false, true><<<g_g512, blk512, 0, stream>>>(
          z_bf, t_bf, 512, 512, wt_sage1 + (size_t)i * 512 * 1024,
          sage_b1 + (size_t)i * SW, nullptr, nullptr, u_bf, N, 512);
      k_mfma<256, 0, true, false, true, true><<<g_g512, blk512, 0, stream>>>(
          u_bf, nullptr, 512, 0, wt_sage2 + (size_t)i * 512 * 512,
          sage_b2 + (size_t)i * SW, z32, z32, z_bf, N, 512);
    }
    // enc = z @ se_out_w + b   (bf16 only)
    k_mfma<256, 0, false, false, false, true><<<g_g512, blk512, 0, stream>>>(
        z_bf, nullptr, 512, 0, wt_se_out, se_out_b, nullptr, nullptr, t_bf, N, 512);
    // nr = gelu(enc @ enc_w1 + b) @ enc_w2 + b
    k_mfma<256, 1, false, false, false, true><<<g_g512, blk512, 0, stream>>>(
        t_bf, nullptr, 512, 0, wt_enc1 + (size_t)k * 512 * 512,
        enc_b1 + (size_t)k * SW, nullptr, nullptr, u_bf, N, 512);
    k_mfma<256, 0, false, false, false, true><<<g_g512, blk512, 0, stream>>>(
        u_bf, nullptr, 512, 0, wt_enc2 + (size_t)k * 512 * 512,
        enc_b2 + (size_t)k * SW, nullptr, nullptr, t_bf, N, 512);
    // rotation params; hn=LN(h), y=O@hn; msg=O^T@mean(y)
    k_oparams<<<cdiv(N * 128, 256), blk, 0, stream>>>(t_bf, o, N * 128);
    k_ln_rot<<<gw, blk, 0, stream>>>(h32, o, ln_g + (size_t)k * HID, ln_b + (size_t)k * HID, hn, y, N);
    k_agg<256, true><<<gw, blk, 0, stream>>>(y, rp, srcs, o, msg, N);
    // h = h + gelu([hn|msg] @ bdl_w1 + b1) @ bdl_w2 + b2
    k_mfma<128, 1, false, true, false, true><<<g_g256, blk512, 0, stream>>>(
        hn, msg, 256, 256, wt_bdl1 + (size_t)k * 256 * 512,
        bdl_b1 + (size_t)k * HID, nullptr, nullptr, g2, N, 256);
    k_mfma<128, 0, true, false, true, true><<<g_g256, blk512, 0, stream>>>(
        g2, nullptr, 256, 0, wt_bdl2 + (size_t)k * 256 * 256,
        bdl_b2 + (size_t)k * HID, h32, h32, h_bf, N, 256);
  }

  k_final<<<gw, blk, 0, stream>>>(h32, oln_g, oln_b, w_out, b_out, out, N);
}